// Round 12
// baseline (518.660 us; speedup 1.0000x reference)
//
#include <hip/hip_runtime.h>
#include <math.h>

#define N_PTS   1000000
#define CI      10
#define C       64
#define NSEG    30000
#define BN_EPS  1e-3f
#define FROFF   31104      // float index of fragment blob (after starts ints)
#define LOG2E   1.44269504f
#define NBLK_G  8192

// ws layout (floats):
// [0:65)    moments acc (colsum[10] + M upper-tri[55])   (zeroed)
// [66]      ticket (int)                                  (zeroed)
// [256:320) g_sum acc                                     (zeroed)
// ints at [1024:31024): segment starts
// [FROFF:FROFF+16*256): per-lane fragment blob, 16 items x 64 lanes x 16B

using f32x4 = __attribute__((ext_vector_type(4))) float;
using s16x8 = __attribute__((ext_vector_type(8))) short;

__device__ inline short f2bf(float x) {           // RNE fp32 -> bf16 (weights)
    unsigned u = __float_as_uint(x);
    unsigned r = (u + 0x7fffu + ((u >> 16) & 1u)) >> 16;
    return (short)r;
}
__device__ inline unsigned pack_trunc(float lo, float hi) {  // 2x bf16 truncate
    return (__float_as_uint(hi) & 0xffff0000u) | (__float_as_uint(lo) >> 16);
}
__device__ inline float frcp(float x) { return __builtin_amdgcn_rcpf(x); }
// LDS-only drain (does NOT touch vmcnt -> global prefetch stays in flight)
__device__ inline void lds_fence() {
    asm volatile("s_waitcnt lgkmcnt(0)" ::: "memory");
}

struct Rows { float2 r0, r1, r2, r3; };
__device__ inline Rows zrows() {
    Rows R; R.r0 = R.r1 = R.r2 = R.r3 = make_float2(0.f, 0.f); return R;
}

// Kernel 1: moments via pair-of-rows float4 loads (5 aligned float4 per 2
// rows, all independent -> max loads in flight). Atomic reduction (proven
// equal to partials in R8 vs R11). Fused: segment starts.
__global__ void __launch_bounds__(256) k_moments(const float* __restrict__ inp,
                                                 const int* __restrict__ idx,
                                                 float* __restrict__ ws,
                                                 int* __restrict__ starts) {
    const int tid = threadIdx.x;
    float v[65];
#pragma unroll
    for (int k = 0; k < 65; ++k) v[k] = 0.f;

    const int NPP = N_PTS / 2;   // 500000 pairs
    for (int pp = blockIdx.x * blockDim.x + tid; pp < NPP; pp += gridDim.x * blockDim.x) {
        const float4* base = (const float4*)(inp + (size_t)pp * 20);
        float4 a = base[0], b4 = base[1], c = base[2], d = base[3], e = base[4];
        float r0[CI] = {a.x, a.y, a.z, a.w, b4.x, b4.y, b4.z, b4.w, c.x, c.y};
        float r1[CI] = {c.z, c.w, d.x, d.y, d.z, d.w, e.x, e.y, e.z, e.w};
#pragma unroll
        for (int i = 0; i < CI; ++i) v[i] += r0[i] + r1[i];
        int kk = 10;
#pragma unroll
        for (int i = 0; i < CI; ++i)
#pragma unroll
            for (int j = i; j < CI; ++j) {
                v[kk] = fmaf(r0[i], r0[j], v[kk]);
                v[kk] = fmaf(r1[i], r1[j], v[kk]);
                ++kk;
            }

        const int p0 = 2 * pp;
        int2 iv = *(const int2*)(idx + p0);
        if (p0 == 0) starts[0] = 0;
        else { int prev = idx[p0 - 1]; if (prev != iv.x) starts[iv.x] = p0; }
        if (iv.x != iv.y) starts[iv.y] = p0 + 1;
    }

#pragma unroll
    for (int k = 0; k < 65; ++k) {
#pragma unroll
        for (int off = 32; off >= 1; off >>= 1)
            v[k] += __shfl_xor(v[k], off, 64);
    }
    __shared__ float red[4 * 65];
    const int wv = tid >> 6, ln = tid & 63;
    if (ln == 0) {
#pragma unroll
        for (int k = 0; k < 65; ++k) red[wv * 65 + k] = v[k];
    }
    __syncthreads();
    if (tid < 65)
        atomicAdd(&ws[tid], red[tid] + red[65 + tid] + red[130 + tid] + red[195 + tid]);
}

// Kernel 2: gstats (single-wave blocks, contiguous batch ranges, 3-deep
// prefetch). Per-block BN finalize from moments (LDS). g_sum via atomics.
// LAST block (device ticket) computes exact fp32 xg and writes the per-lane
// fragment blob for k_main (replaces k_prep/k_red nodes).
// FR items: 0..3 wfr; 4..11 bfr(pw1 * -log2e); 12 bb; 13 d1; 14 xge; 15 d1e
__global__ void __launch_bounds__(64, 4) k_gstats(const float* __restrict__ inp,
                                                  const float* __restrict__ W,
                                                  const float* __restrict__ gamma,
                                                  const float* __restrict__ beta,
                                                  const float* __restrict__ dw1,
                                                  const float* __restrict__ pw1,
                                                  const float* __restrict__ dw2,
                                                  const float* __restrict__ pw2,
                                                  float* __restrict__ ws) {
    const int tid  = threadIdx.x;     // 0..63, single wave
    const int m = tid & 15;
    const int q = tid >> 4;
    const float inv_n = 1.f / (float)N_PTS;
    const f32x4 zero = {0.f, 0.f, 0.f, 0.f};

    __shared__ float WP[C * CI];   // W' = a*W
    __shared__ float BSH[C];
    __shared__ float T[C];
    __shared__ int   lastFlag;

    {   // BN finalize, channel = tid
        float w[CI];
#pragma unroll
        for (int i = 0; i < CI; ++i) w[i] = W[tid * CI + i];
        float mu = 0.f;
#pragma unroll
        for (int i = 0; i < CI; ++i) mu = fmaf(w[i], ws[i], mu);
        mu *= inv_n;
        float ex2 = 0.f;
        int kk = 10;
#pragma unroll
        for (int i = 0; i < CI; ++i)
#pragma unroll
            for (int j = i; j < CI; ++j) {
                float mm = ws[kk];
                float t = w[i] * w[j] * mm;
                ex2 += (i == j) ? t : 2.f * t;
                ++kk;
            }
        ex2 *= inv_n;
        float var = ex2 - mu * mu;
        float rstd = rsqrtf(var + BN_EPS);
        float a = rstd * gamma[tid];
        BSH[tid] = beta[tid] - mu * a;
#pragma unroll
        for (int i = 0; i < CI; ++i) WP[tid * CI + i] = a * w[i];
    }
    __syncthreads();

    s16x8 wfr[4];
#pragma unroll
    for (int nt = 0; nt < 4; ++nt) {
        s16x8 t;
#pragma unroll
        for (int j = 0; j < 8; ++j) {
            int k = 8 * q + j;
            t[j] = (k < CI) ? f2bf(WP[(nt * 16 + m) * CI + k]) : (short)0;
        }
        wfr[nt] = t;
    }
    float bb[4];
#pragma unroll
    for (int nt = 0; nt < 4; ++nt) bb[nt] = BSH[nt * 16 + m];

    auto loadrows = [&](int pb) -> Rows {
        Rows R = zrows();
        const float* row = inp + (size_t)(pb + m) * CI;
        if (q == 0) {
            R.r0 = *(const float2*)(row);     R.r1 = *(const float2*)(row + 2);
            R.r2 = *(const float2*)(row + 4); R.r3 = *(const float2*)(row + 6);
        } else if (q == 1) {
            R.r0 = *(const float2*)(row + 8);
        }
        return R;
    };
    auto mkfrag = [&](const Rows& L) -> s16x8 {
        union { s16x8 v; unsigned u[4]; } t;
        t.v = s16x8{0, 0, 0, 0, 0, 0, 0, 0};
        if (q < 2) t.u[0] = pack_trunc(L.r0.x, L.r0.y);
        if (q == 0) {
            t.u[1] = pack_trunc(L.r1.x, L.r1.y);
            t.u[2] = pack_trunc(L.r2.x, L.r2.y);
            t.u[3] = pack_trunc(L.r3.x, L.r3.y);
        }
        return t.v;
    };

    // contiguous batch range, 3-deep prefetch
    const long long NB = N_PTS / 16;           // 62500
    const int b0 = (int)((long long)blockIdx.x * NB / NBLK_G);
    const int b1 = (int)((long long)(blockIdx.x + 1) * NB / NBLK_G);

    float sm[4] = {0.f, 0.f, 0.f, 0.f};
    Rows P0 = zrows(), P1 = zrows(), P2 = zrows();
    if (b0 < b1)     P0 = loadrows(b0 * 16);
    if (b0 + 1 < b1) P1 = loadrows((b0 + 1) * 16);
    if (b0 + 2 < b1) P2 = loadrows((b0 + 2) * 16);

    for (int b = b0; b < b1; ++b) {
        Rows L = P0; P0 = P1; P1 = P2;
        if (b + 3 < b1) P2 = loadrows((b + 3) * 16);
        s16x8 t = mkfrag(L);
#pragma unroll
        for (int nt = 0; nt < 4; ++nt) {
            f32x4 xt = __builtin_amdgcn_mfma_f32_16x16x32_bf16(t, wfr[nt], zero, 0, 0, 0);
#pragma unroll
            for (int r = 0; r < 4; ++r)
                sm[nt] += fmaxf(xt[r] + bb[nt], 0.f);
        }
    }

#pragma unroll
    for (int nt = 0; nt < 4; ++nt) {
        sm[nt] += __shfl_xor(sm[nt], 16, 64);
        sm[nt] += __shfl_xor(sm[nt], 32, 64);
    }
    float S = sm[0];
    if (q == 1) S = sm[1];
    if (q == 2) S = sm[2];
    if (q == 3) S = sm[3];
    atomicAdd(&ws[256 + tid], S);     // tid == channel

    // ---- last block: xg + fragment blob
    __threadfence();
    if (tid == 0) {
        int old = atomicAdd((int*)&ws[66], 1);
        lastFlag = (old == (int)gridDim.x - 1);
    }
    __syncthreads();
    if (!lastFlag) return;

    float g = atomicAdd(&ws[256 + tid], 0.f) * inv_n;   // coherent read
    T[tid] = fmaxf(dw2[tid] * g, 0.f);
    __syncthreads();
    float xg = 0.f;
#pragma unroll
    for (int k = 0; k < C; ++k) xg = fmaf(pw2[tid * C + k], T[k], xg);
    T[tid] = xg;                                        // reuse as XG
    __syncthreads();

    float4* FR = (float4*)(ws + FROFF);
    union { float4 f; s16x8 v; } u;
#pragma unroll
    for (int nt = 0; nt < 4; ++nt) { u.v = wfr[nt]; FR[nt * 64 + tid] = u.f; }
#pragma unroll
    for (int nt = 0; nt < 4; ++nt)
#pragma unroll
        for (int kc = 0; kc < 2; ++kc) {
            const float* src = pw1 + (nt * 16 + m) * C + kc * 32 + q * 8;
            float4 p0 = *(const float4*)src, p1 = *(const float4*)(src + 4);
            s16x8 tt;
            tt[0] = f2bf(-LOG2E * p0.x); tt[1] = f2bf(-LOG2E * p0.y);
            tt[2] = f2bf(-LOG2E * p0.z); tt[3] = f2bf(-LOG2E * p0.w);
            tt[4] = f2bf(-LOG2E * p1.x); tt[5] = f2bf(-LOG2E * p1.y);
            tt[6] = f2bf(-LOG2E * p1.z); tt[7] = f2bf(-LOG2E * p1.w);
            u.v = tt; FR[(4 + nt * 2 + kc) * 64 + tid] = u.f;
        }
    float4 f;
    f.x = BSH[m]; f.y = BSH[16 + m]; f.z = BSH[32 + m]; f.w = BSH[48 + m];
    FR[12 * 64 + tid] = f;
    f.x = dw1[m]; f.y = dw1[16 + m]; f.z = dw1[32 + m]; f.w = dw1[48 + m];
    FR[13 * 64 + tid] = f;
    f.x = -LOG2E * T[m];      f.y = -LOG2E * T[16 + m];
    f.z = -LOG2E * T[32 + m]; f.w = -LOG2E * T[48 + m];
    FR[14 * 64 + tid] = f;
    f.x = -LOG2E * dw1[m];      f.y = -LOG2E * dw1[16 + m];
    f.z = -LOG2E * dw1[32 + m]; f.w = -LOG2E * dw1[48 + m];
    FR[15 * 64 + tid] = f;
}

// Kernel 3: k_main — SINGLE-WAVE 64-thread blocks (max residency), one block
// per 2 contiguous segments, 16-pt batches streamed across the boundary,
// segmented sum/max, 3-deep prefetch, exp2-folded sigmoids.
#define LD 68
__global__ void __launch_bounds__(64, 4) k_main(const float* __restrict__ inp,
                                                const float* __restrict__ ws,
                                                const int* __restrict__ starts,
                                                float* __restrict__ out) {
    const int lane = threadIdx.x;
    const int m = lane & 15;
    const int q = lane >> 4;
    const f32x4 zero = {0.f, 0.f, 0.f, 0.f};

    const float4* FR = (const float4*)(ws + FROFF);
    union { float4 f; s16x8 v; } u;
    s16x8 wfr[4];
#pragma unroll
    for (int nt = 0; nt < 4; ++nt) { u.f = FR[nt * 64 + lane]; wfr[nt] = u.v; }
    s16x8 bfr[4][2];
#pragma unroll
    for (int nt = 0; nt < 4; ++nt)
#pragma unroll
        for (int kc = 0; kc < 2; ++kc) { u.f = FR[(4 + nt * 2 + kc) * 64 + lane]; bfr[nt][kc] = u.v; }
    const float4 bb4  = FR[12 * 64 + lane];
    const float4 d14  = FR[13 * 64 + lane];
    const float4 xe4  = FR[14 * 64 + lane];
    const float4 de4  = FR[15 * 64 + lane];
    const float bb[4]  = {bb4.x, bb4.y, bb4.z, bb4.w};
    const float d1v[4] = {d14.x, d14.y, d14.z, d14.w};
    const float xge[4] = {xe4.x, xe4.y, xe4.z, xe4.w};
    const float d1e[4] = {de4.x, de4.y, de4.z, de4.w};

    __shared__ float my[16 * LD];

    const int s0 = blockIdx.x * 2;          // 15000 blocks
    int st1 = starts[s0 + 1];
    int st2 = (s0 + 2 < NSEG) ? starts[s0 + 2] : N_PTS;
    const int start   = starts[s0];
    const int end_all = st2;

    int cur = s0;
    int end_cur = st1;

    float sm[4]  = {0.f, 0.f, 0.f, 0.f};
    float mxv[4] = {-INFINITY, -INFINITY, -INFINITY, -INFINITY};

    auto flushseg = [&](int s) {
#pragma unroll
        for (int nt = 0; nt < 4; ++nt) {
            sm[nt] += __shfl_xor(sm[nt], 16, 64);
            sm[nt] += __shfl_xor(sm[nt], 32, 64);
            mxv[nt] = fmaxf(mxv[nt], __shfl_xor(mxv[nt], 16, 64));
            mxv[nt] = fmaxf(mxv[nt], __shfl_xor(mxv[nt], 32, 64));
        }
        float S = sm[0], M = mxv[0];
        if (q == 1) { S = sm[1]; M = mxv[1]; }
        if (q == 2) { S = sm[2]; M = mxv[2]; }
        if (q == 3) { S = sm[3]; M = mxv[3]; }
        out[(size_t)s * C + lane] = S + M;
#pragma unroll
        for (int nt = 0; nt < 4; ++nt) { sm[nt] = 0.f; mxv[nt] = -INFINITY; }
    };

    auto loadrows = [&](int pb) -> Rows {
        Rows R = zrows();
        const float* row = inp + (size_t)min(pb + m, N_PTS - 1) * CI;
        if (q == 0) {
            R.r0 = *(const float2*)(row);     R.r1 = *(const float2*)(row + 2);
            R.r2 = *(const float2*)(row + 4); R.r3 = *(const float2*)(row + 6);
        } else if (q == 1) {
            R.r0 = *(const float2*)(row + 8);
        }
        return R;
    };
    auto mkfrag = [&](const Rows& L) -> s16x8 {
        union { s16x8 v; unsigned u[4]; } t;
        t.v = s16x8{0, 0, 0, 0, 0, 0, 0, 0};
        if (q < 2) t.u[0] = pack_trunc(L.r0.x, L.r0.y);
        if (q == 0) {
            t.u[1] = pack_trunc(L.r1.x, L.r1.y);
            t.u[2] = pack_trunc(L.r2.x, L.r2.y);
            t.u[3] = pack_trunc(L.r3.x, L.r3.y);
        }
        return t.v;
    };

    Rows PA = loadrows(start);
    Rows PB = (start + 16 < end_all) ? loadrows(start + 16) : PA;
    Rows PC = (start + 32 < end_all) ? loadrows(start + 32) : PB;

    for (int base = start; base < end_all; base += 16) {
        Rows L = PA;
        PA = PB; PB = PC;
        if (base + 48 < end_all) PC = loadrows(base + 48);

        const int nb = min(16, end_all - base);

        s16x8 t = mkfrag(L);
        f32x4 xt[4];
#pragma unroll
        for (int nt = 0; nt < 4; ++nt)
            xt[nt] = __builtin_amdgcn_mfma_f32_16x16x32_bf16(t, wfr[nt], zero, 0, 0, 0);

        // BN + ReLU + swish (exp2-folded): sw = xn*d1 * rcp(1+2^(xn*d1e))
        float xn[4][4];
#pragma unroll
        for (int nt = 0; nt < 4; ++nt)
#pragma unroll
            for (int r = 0; r < 4; ++r) {
                float x = fmaxf(xt[nt][r] + bb[nt], 0.f);
                xn[nt][r] = x;
                float e  = exp2f(x * d1e[nt]);
                float sw = x * d1v[nt] * frcp(1.f + e);
                my[(4 * q + r) * LD + nt * 16 + m] = sw;
            }
        lds_fence();

        s16x8 av[2];
#pragma unroll
        for (int kc = 0; kc < 2; ++kc) {
            const float* src = &my[m * LD + kc * 32 + q * 8];
            float4 p0 = *(const float4*)src;
            float4 p1 = *(const float4*)(src + 4);
            union { s16x8 v; unsigned u[4]; } tt;
            tt.u[0] = pack_trunc(p0.x, p0.y);
            tt.u[1] = pack_trunc(p0.z, p0.w);
            tt.u[2] = pack_trunc(p1.x, p1.y);
            tt.u[3] = pack_trunc(p1.z, p1.w);
            av[kc] = tt.v;
        }

        // z = -log2e * xl  (scale folded into bfr)
        f32x4 xi[4];
#pragma unroll
        for (int nt = 0; nt < 4; ++nt) {
            xi[nt] = __builtin_amdgcn_mfma_f32_16x16x32_bf16(av[0], bfr[nt][0], zero, 0, 0, 0);
            xi[nt] = __builtin_amdgcn_mfma_f32_16x16x32_bf16(av[1], bfr[nt][1], xi[nt], 0, 0, 0);
        }
        // no second fence: per-wave DS pipe is in-order

        // wei = rcp(1 + 2^(z + xge));  xi = xn*(1+wei)
#pragma unroll
        for (int nt = 0; nt < 4; ++nt)
#pragma unroll
            for (int r = 0; r < 4; ++r) {
                float e2  = exp2f(xi[nt][r] + xge[nt]);
                float wei = frcp(1.f + e2);
                float x   = xn[nt][r];
                xi[nt][r] = fmaf(x, wei, x);
            }

        const int fin = base + nb;
        if (fin <= end_cur) {
            if (nb == 16) {
#pragma unroll
                for (int nt = 0; nt < 4; ++nt)
#pragma unroll
                    for (int r = 0; r < 4; ++r) {
                        sm[nt] += xi[nt][r];
                        mxv[nt] = fmaxf(mxv[nt], xi[nt][r]);
                    }
            } else {
#pragma unroll
                for (int nt = 0; nt < 4; ++nt)
#pragma unroll
                    for (int r = 0; r < 4; ++r) {
                        bool act = (4 * q + r) < nb;
                        sm[nt] += act ? xi[nt][r] : 0.f;
                        mxv[nt] = fmaxf(mxv[nt], act ? xi[nt][r] : -INFINITY);
                    }
            }
            if (fin == end_cur) { flushseg(cur); ++cur; end_cur = st2; }
        } else {
            const int B = end_cur - base;   // 1..nb-1
#pragma unroll
            for (int nt = 0; nt < 4; ++nt)
#pragma unroll
                for (int r = 0; r < 4; ++r) {
                    bool act = (4 * q + r) < B;
                    sm[nt] += act ? xi[nt][r] : 0.f;
                    mxv[nt] = fmaxf(mxv[nt], act ? xi[nt][r] : -INFINITY);
                }
            flushseg(cur); ++cur;
#pragma unroll
            for (int nt = 0; nt < 4; ++nt)
#pragma unroll
                for (int r = 0; r < 4; ++r) {
                    int pt = 4 * q + r;
                    bool act = (pt >= B) && (pt < nb);
                    sm[nt] += act ? xi[nt][r] : 0.f;
                    mxv[nt] = fmaxf(mxv[nt], act ? xi[nt][r] : -INFINITY);
                }
            end_cur = st2;
        }
    }
}

extern "C" void kernel_launch(void* const* d_in, const int* in_sizes, int n_in,
                              void* d_out, int out_size, void* d_ws, size_t ws_size,
                              hipStream_t stream) {
    const float* inp   = (const float*)d_in[0];
    const int*   unq   = (const int*)d_in[1];
    const float* W     = (const float*)d_in[2];
    const float* gamma = (const float*)d_in[3];
    const float* beta  = (const float*)d_in[4];
    const float* dw1   = (const float*)d_in[5];
    const float* pw1   = (const float*)d_in[6];
    const float* dw2   = (const float*)d_in[7];
    const float* pw2   = (const float*)d_in[8];
    float* out = (float*)d_out;
    float* ws  = (float*)d_ws;
    int* starts = (int*)ws + 1024;

    hipMemsetAsync(ws, 0, 384 * sizeof(float), stream);   // moments+g_sum+ticket

    k_moments <<<2048,  256, 0, stream>>>(inp, unq, ws, starts);
    k_gstats  <<<NBLK_G, 64, 0, stream>>>(inp, W, gamma, beta, dw1, pw1, dw2, pw2, ws);
    k_main    <<<15000,  64, 0, stream>>>(inp, ws, starts, out);
}

// Round 13
// 296.560 us; speedup vs baseline: 1.7489x; 1.7489x over previous
//
#include <hip/hip_runtime.h>
#include <math.h>

#define N_PTS   1000000
#define CI      10
#define C       64
#define NSEG    30000
#define BN_EPS  1e-3f
#define FROFF   31104      // float index of fragment blob (after starts ints)
#define LOG2E   1.44269504f

// ws layout (floats):
// [0:10)    colsum(inp)              (accumulator, zeroed)
// [10:65)   M = sum r*r^T upper-tri (55)  (zeroed)
// [256:320) g_sum                    (accumulator, zeroed)
// ints at [1024:31024): segment starts
// [FROFF:FROFF+16*256): per-lane fragment blob, 16 items x 64 lanes x 16B

using f32x4 = __attribute__((ext_vector_type(4))) float;
using s16x8 = __attribute__((ext_vector_type(8))) short;

__device__ inline short f2bf(float x) {           // RNE fp32 -> bf16 (weights)
    unsigned u = __float_as_uint(x);
    unsigned r = (u + 0x7fffu + ((u >> 16) & 1u)) >> 16;
    return (short)r;
}
__device__ inline unsigned pack_trunc(float lo, float hi) {  // 2x bf16 truncate
    return (__float_as_uint(hi) & 0xffff0000u) | (__float_as_uint(lo) >> 16);
}
__device__ inline float frcp(float x) { return __builtin_amdgcn_rcpf(x); }
// LDS-only drain: write->read visibility within a wave; does NOT touch vmcnt
// so global prefetch loads stay in flight (the R7->R8 win).
__device__ inline void lds_fence() {
    asm volatile("s_waitcnt lgkmcnt(0)" ::: "memory");
}

struct Rows { float2 r0, r1, r2, r3; };
__device__ inline Rows zrows() {
    Rows R; R.r0 = R.r1 = R.r2 = R.r3 = make_float2(0.f, 0.f); return R;
}

// Kernel 1: moments via pair-of-rows float4 loads (5 aligned float4 per 2
// rows -> 2.5x fewer VMEM instrs than per-row float2). 1024x256 (R8 grid),
// atomic reduce (R8-proven). Fused: segment starts.
__global__ void __launch_bounds__(256) k_moments(const float* __restrict__ inp,
                                                 const int* __restrict__ idx,
                                                 float* __restrict__ ws,
                                                 int* __restrict__ starts) {
    const int tid = threadIdx.x;
    float v[65];
#pragma unroll
    for (int k = 0; k < 65; ++k) v[k] = 0.f;

    const int NPP = N_PTS / 2;   // 500000 pairs
    for (int pp = blockIdx.x * blockDim.x + tid; pp < NPP; pp += gridDim.x * blockDim.x) {
        const float4* base = (const float4*)(inp + (size_t)pp * 20);
        float4 a = base[0], b4 = base[1], c = base[2], d = base[3], e = base[4];
        float r0[CI] = {a.x, a.y, a.z, a.w, b4.x, b4.y, b4.z, b4.w, c.x, c.y};
        float r1[CI] = {c.z, c.w, d.x, d.y, d.z, d.w, e.x, e.y, e.z, e.w};
#pragma unroll
        for (int i = 0; i < CI; ++i) v[i] += r0[i] + r1[i];
        int kk = 10;
#pragma unroll
        for (int i = 0; i < CI; ++i)
#pragma unroll
            for (int j = i; j < CI; ++j) {
                v[kk] = fmaf(r0[i], r0[j], v[kk]);
                v[kk] = fmaf(r1[i], r1[j], v[kk]);
                ++kk;
            }

        const int p0 = 2 * pp;
        int2 iv = *(const int2*)(idx + p0);
        if (p0 == 0) starts[0] = 0;
        else { int prev = idx[p0 - 1]; if (prev != iv.x) starts[iv.x] = p0; }
        if (iv.x != iv.y) starts[iv.y] = p0 + 1;
    }

#pragma unroll
    for (int k = 0; k < 65; ++k) {
#pragma unroll
        for (int off = 32; off >= 1; off >>= 1)
            v[k] += __shfl_xor(v[k], off, 64);
    }
    __shared__ float red[4 * 65];
    const int wv = tid >> 6, ln = tid & 63;
    if (ln == 0) {
#pragma unroll
        for (int k = 0; k < 65; ++k) red[wv * 65 + k] = v[k];
    }
    __syncthreads();
    if (tid < 65)
        atomicAdd(&ws[tid], red[tid] + red[65 + tid] + red[130 + tid] + red[195 + tid]);
}

// Kernel 2 (R8 exact): fused finalize + gstats. Per-block BN finalize from
// the 65 moments (LDS ONLY), then g_sum[c] = sum_p relu(x'_pc + b_c) via
// MFMA linear, strided batches, 1-deep prefetch, atomics.
__global__ void __launch_bounds__(256) k_gstats(const float* __restrict__ inp,
                                                const float* __restrict__ W,
                                                const float* __restrict__ gamma,
                                                const float* __restrict__ beta,
                                                float* __restrict__ ws) {
    const int tid  = threadIdx.x;
    const int wv   = tid >> 6;
    const int lane = tid & 63;
    const int m = lane & 15;
    const int q = lane >> 4;

    __shared__ float wp[C * CI];   // W' = a*W
    __shared__ float bsh[C];

    if (tid < C) {
        const int c = tid;
        float w[CI];
#pragma unroll
        for (int i = 0; i < CI; ++i) w[i] = W[c * CI + i];
        const float inv_n = 1.f / (float)N_PTS;

        float mu = 0.f;
#pragma unroll
        for (int i = 0; i < CI; ++i) mu = fmaf(w[i], ws[i], mu);
        mu *= inv_n;

        float ex2 = 0.f;
        int kk = 10;
#pragma unroll
        for (int i = 0; i < CI; ++i)
#pragma unroll
            for (int j = i; j < CI; ++j) {
                float mm = ws[kk];
                float t = w[i] * w[j] * mm;
                ex2 += (i == j) ? t : 2.f * t;
                ++kk;
            }
        ex2 *= inv_n;

        float var = ex2 - mu * mu;
        float rstd = rsqrtf(var + BN_EPS);
        float a = rstd * gamma[c];
        float b = beta[c] - mu * a;
        bsh[c] = b;
#pragma unroll
        for (int i = 0; i < CI; ++i) wp[c * CI + i] = a * w[i];
    }
    __syncthreads();

    s16x8 wfr[4];
#pragma unroll
    for (int nt = 0; nt < 4; ++nt) {
        s16x8 t;
#pragma unroll
        for (int j = 0; j < 8; ++j) {
            int k = 8 * q + j;
            t[j] = (k < CI) ? f2bf(wp[(nt * 16 + m) * CI + k]) : (short)0;
        }
        wfr[nt] = t;
    }
    float bb[4];
#pragma unroll
    for (int nt = 0; nt < 4; ++nt) bb[nt] = bsh[nt * 16 + m];

    const int wid = blockIdx.x * 4 + wv;
    const int nw  = gridDim.x * 4;
    const int NB  = N_PTS / 16;          // 62500

    float2 P0, P1, P2, P3;
    auto loadrows = [&](int pb) {
        const float* row = inp + (size_t)(pb + m) * CI;
        if (q == 0) {
            P0 = *(const float2*)(row);     P1 = *(const float2*)(row + 2);
            P2 = *(const float2*)(row + 4); P3 = *(const float2*)(row + 6);
        } else if (q == 1) {
            P0 = *(const float2*)(row + 8);
        }
    };
    P0 = P1 = P2 = P3 = make_float2(0.f, 0.f);

    float sm[4] = {0.f, 0.f, 0.f, 0.f};
    const f32x4 zero = {0.f, 0.f, 0.f, 0.f};

    if (wid < NB) loadrows(wid * 16);
    for (int b = wid; b < NB; b += nw) {
        float2 L0 = P0, L1 = P1, L2 = P2, L3 = P3;
        if (b + nw < NB) loadrows((b + nw) * 16);

        union { s16x8 v; unsigned u[4]; } t;
        t.v = s16x8{0, 0, 0, 0, 0, 0, 0, 0};
        if (q < 2) t.u[0] = pack_trunc(L0.x, L0.y);
        if (q == 0) {
            t.u[1] = pack_trunc(L1.x, L1.y);
            t.u[2] = pack_trunc(L2.x, L2.y);
            t.u[3] = pack_trunc(L3.x, L3.y);
        }

        f32x4 xt[4];
#pragma unroll
        for (int nt = 0; nt < 4; ++nt) {
            xt[nt] = __builtin_amdgcn_mfma_f32_16x16x32_bf16(t.v, wfr[nt], zero, 0, 0, 0);
#pragma unroll
            for (int r = 0; r < 4; ++r)
                sm[nt] += fmaxf(xt[nt][r] + bb[nt], 0.f);
        }
    }

#pragma unroll
    for (int nt = 0; nt < 4; ++nt) {
        sm[nt] += __shfl_xor(sm[nt], 16, 64);
        sm[nt] += __shfl_xor(sm[nt], 32, 64);
    }
    float S = sm[0];
    if (q == 1) S = sm[1];
    if (q == 2) S = sm[2];
    if (q == 3) S = sm[3];

    __shared__ float red[4 * 64];
    red[wv * 64 + lane] = S;              // lane == channel
    __syncthreads();
    if (tid < 64)
        atomicAdd(&ws[256 + tid], red[tid] + red[64 + tid] + red[128 + tid] + red[192 + tid]);
}

// Kernel 3: k_prep — BN finalize (lane = channel), exact fp32 xg, and all
// per-lane fragments for k_main, stored as [item][lane] 16B records.
// items 0..3: wfr[nt]; 4..11: bfr[nt][kc] scaled by -log2e; 12: bb;
// 13: d1; 14: xge = -log2e*xg; 15: d1e = -log2e*d1
__global__ void k_prep(const float* __restrict__ W,
                       const float* __restrict__ gamma,
                       const float* __restrict__ beta,
                       const float* __restrict__ dw1,
                       const float* __restrict__ pw1,
                       const float* __restrict__ dw2,
                       const float* __restrict__ pw2,
                       float* __restrict__ ws) {
    const int lane = threadIdx.x;     // 0..63 ; lane == channel c
    const int m = lane & 15, q = lane >> 4;
    const float inv_n = 1.f / (float)N_PTS;

    __shared__ float WP[C * CI];   // W' = a*W
    __shared__ float BSH[C], T[C], XG[C];

    // ---- BN finalize for channel `lane`
    {
        float w[CI];
#pragma unroll
        for (int i = 0; i < CI; ++i) w[i] = W[lane * CI + i];
        float mu = 0.f;
#pragma unroll
        for (int i = 0; i < CI; ++i) mu = fmaf(w[i], ws[i], mu);
        mu *= inv_n;
        float ex2 = 0.f;
        int kk = 10;
#pragma unroll
        for (int i = 0; i < CI; ++i)
#pragma unroll
            for (int j = i; j < CI; ++j) {
                float mm = ws[kk];
                float t = w[i] * w[j] * mm;
                ex2 += (i == j) ? t : 2.f * t;
                ++kk;
            }
        ex2 *= inv_n;
        float var = ex2 - mu * mu;
        float rstd = rsqrtf(var + BN_EPS);
        float a = rstd * gamma[lane];
        BSH[lane] = beta[lane] - mu * a;
#pragma unroll
        for (int i = 0; i < CI; ++i) WP[lane * CI + i] = a * w[i];
        T[lane] = fmaxf(dw2[lane] * (ws[256 + lane] * inv_n), 0.f);
    }
    __syncthreads();

    // ---- xg = pw2 @ relu(dw2*g)  (exact fp32)
    {
        float acc = 0.f;
#pragma unroll
        for (int k = 0; k < C; ++k) acc = fmaf(pw2[lane * C + k], T[k], acc);
        XG[lane] = acc;
    }
    __syncthreads();

    float4* FR = (float4*)(ws + FROFF);
    union { float4 f; s16x8 v; } u;

#pragma unroll
    for (int nt = 0; nt < 4; ++nt) {
        s16x8 tt;
#pragma unroll
        for (int j = 0; j < 8; ++j) {
            int k = 8 * q + j;
            tt[j] = (k < CI) ? f2bf(WP[(nt * 16 + m) * CI + k]) : (short)0;
        }
        u.v = tt; FR[nt * 64 + lane] = u.f;
    }
#pragma unroll
    for (int nt = 0; nt < 4; ++nt)
#pragma unroll
        for (int kc = 0; kc < 2; ++kc) {
            const float* src = pw1 + (nt * 16 + m) * C + kc * 32 + q * 8;
            float4 p0 = *(const float4*)src, p1 = *(const float4*)(src + 4);
            s16x8 tt;
            tt[0] = f2bf(-LOG2E * p0.x); tt[1] = f2bf(-LOG2E * p0.y);
            tt[2] = f2bf(-LOG2E * p0.z); tt[3] = f2bf(-LOG2E * p0.w);
            tt[4] = f2bf(-LOG2E * p1.x); tt[5] = f2bf(-LOG2E * p1.y);
            tt[6] = f2bf(-LOG2E * p1.z); tt[7] = f2bf(-LOG2E * p1.w);
            u.v = tt; FR[(4 + nt * 2 + kc) * 64 + lane] = u.f;
        }
    float4 f;
    f.x = BSH[m]; f.y = BSH[16 + m]; f.z = BSH[32 + m]; f.w = BSH[48 + m];
    FR[12 * 64 + lane] = f;
    f.x = dw1[m]; f.y = dw1[16 + m]; f.z = dw1[32 + m]; f.w = dw1[48 + m];
    FR[13 * 64 + lane] = f;
    f.x = -LOG2E * XG[m];      f.y = -LOG2E * XG[16 + m];
    f.z = -LOG2E * XG[32 + m]; f.w = -LOG2E * XG[48 + m];
    FR[14 * 64 + lane] = f;
    f.x = -LOG2E * dw1[m];      f.y = -LOG2E * dw1[16 + m];
    f.z = -LOG2E * dw1[32 + m]; f.w = -LOG2E * dw1[48 + m];
    FR[15 * 64 + lane] = f;
}

// Kernel 4: k_main — EXACT R8 structure (best measured: 89 us) + exp2-folded
// sigmoids. One wave per 2 contiguous segments, 16-pt batches streamed across
// the boundary, segmented sum/max, 2-deep row prefetch, LDS-only fences.
#define LD 68
#define SEGW 2
__global__ void __launch_bounds__(128) k_main(const float* __restrict__ inp,
                                              const float* __restrict__ ws,
                                              const int* __restrict__ starts,
                                              float* __restrict__ out) {
    const int tid  = threadIdx.x;
    const int wv   = tid >> 6;
    const int lane = tid & 63;
    const int m = lane & 15;
    const int q = lane >> 4;
    const f32x4 zero = {0.f, 0.f, 0.f, 0.f};

    const float4* FR = (const float4*)(ws + FROFF);
    union { float4 f; s16x8 v; } u;
    s16x8 wfr[4];
#pragma unroll
    for (int nt = 0; nt < 4; ++nt) { u.f = FR[nt * 64 + lane]; wfr[nt] = u.v; }
    s16x8 bfr[4][2];
#pragma unroll
    for (int nt = 0; nt < 4; ++nt)
#pragma unroll
        for (int kc = 0; kc < 2; ++kc) { u.f = FR[(4 + nt * 2 + kc) * 64 + lane]; bfr[nt][kc] = u.v; }
    const float4 bb4  = FR[12 * 64 + lane];
    const float4 d14  = FR[13 * 64 + lane];
    const float4 xe4  = FR[14 * 64 + lane];
    const float4 de4  = FR[15 * 64 + lane];
    const float bb[4]  = {bb4.x, bb4.y, bb4.z, bb4.w};
    const float d1v[4] = {d14.x, d14.y, d14.z, d14.w};
    const float xge[4] = {xe4.x, xe4.y, xe4.z, xe4.w};
    const float d1e[4] = {de4.x, de4.y, de4.z, de4.w};

    __shared__ float sb[2][16 * LD];
    float* my = sb[wv];

    const int w  = blockIdx.x * 2 + wv;    // 0..14999
    const int s0 = w * SEGW;

    int st1 = starts[s0 + 1];
    int st2 = (s0 + 2 < NSEG) ? starts[s0 + 2] : N_PTS;
    const int start   = starts[s0];
    const int end_all = st2;

    int cur = s0;
    int end_cur = st1;

    float sm[4]  = {0.f, 0.f, 0.f, 0.f};
    float mxv[4] = {-INFINITY, -INFINITY, -INFINITY, -INFINITY};

    auto flushseg = [&](int s) {
#pragma unroll
        for (int nt = 0; nt < 4; ++nt) {
            sm[nt] += __shfl_xor(sm[nt], 16, 64);
            sm[nt] += __shfl_xor(sm[nt], 32, 64);
            mxv[nt] = fmaxf(mxv[nt], __shfl_xor(mxv[nt], 16, 64));
            mxv[nt] = fmaxf(mxv[nt], __shfl_xor(mxv[nt], 32, 64));
        }
        float S = sm[0], M = mxv[0];
        if (q == 1) { S = sm[1]; M = mxv[1]; }
        if (q == 2) { S = sm[2]; M = mxv[2]; }
        if (q == 3) { S = sm[3]; M = mxv[3]; }
        out[(size_t)s * C + lane] = S + M;
#pragma unroll
        for (int nt = 0; nt < 4; ++nt) { sm[nt] = 0.f; mxv[nt] = -INFINITY; }
    };

    auto loadrows = [&](int pb) -> Rows {
        Rows R = zrows();
        const float* row = inp + (size_t)min(pb + m, N_PTS - 1) * CI;
        if (q == 0) {
            R.r0 = *(const float2*)(row);     R.r1 = *(const float2*)(row + 2);
            R.r2 = *(const float2*)(row + 4); R.r3 = *(const float2*)(row + 6);
        } else if (q == 1) {
            R.r0 = *(const float2*)(row + 8);
        }
        return R;
    };
    auto mkfrag = [&](const Rows& L) -> s16x8 {
        union { s16x8 v; unsigned u[4]; } t;
        t.v = s16x8{0, 0, 0, 0, 0, 0, 0, 0};
        if (q < 2) t.u[0] = pack_trunc(L.r0.x, L.r0.y);
        if (q == 0) {
            t.u[1] = pack_trunc(L.r1.x, L.r1.y);
            t.u[2] = pack_trunc(L.r2.x, L.r2.y);
            t.u[3] = pack_trunc(L.r3.x, L.r3.y);
        }
        return t.v;
    };

    Rows PA = loadrows(start);
    Rows PB = (start + 16 < end_all) ? loadrows(start + 16) : PA;

    for (int base = start; base < end_all; base += 16) {
        Rows L = PA;
        PA = PB;
        if (base + 32 < end_all) PB = loadrows(base + 32);

        const int nb = min(16, end_all - base);

        s16x8 t = mkfrag(L);
        f32x4 xt[4];
#pragma unroll
        for (int nt = 0; nt < 4; ++nt)
            xt[nt] = __builtin_amdgcn_mfma_f32_16x16x32_bf16(t, wfr[nt], zero, 0, 0, 0);

        // BN + ReLU + swish (exp2-folded): sw = xn*d1 * rcp(1 + 2^(xn*d1e))
        float xn[4][4];
#pragma unroll
        for (int nt = 0; nt < 4; ++nt)
#pragma unroll
            for (int r = 0; r < 4; ++r) {
                float x = fmaxf(xt[nt][r] + bb[nt], 0.f);
                xn[nt][r] = x;
                float e  = exp2f(x * d1e[nt]);
                float sw = x * d1v[nt] * frcp(1.f + e);
                my[(4 * q + r) * LD + nt * 16 + m] = sw;
            }
        lds_fence();

        s16x8 av[2];
#pragma unroll
        for (int kc = 0; kc < 2; ++kc) {
            const float* src = &my[m * LD + kc * 32 + q * 8];
            float4 p0 = *(const float4*)src;
            float4 p1 = *(const float4*)(src + 4);
            union { s16x8 v; unsigned u[4]; } tt;
            tt.u[0] = pack_trunc(p0.x, p0.y);
            tt.u[1] = pack_trunc(p0.z, p0.w);
            tt.u[2] = pack_trunc(p1.x, p1.y);
            tt.u[3] = pack_trunc(p1.z, p1.w);
            av[kc] = tt.v;
        }

        // z = -log2e * xl  (scale folded into bfr)
        f32x4 xi[4];
#pragma unroll
        for (int nt = 0; nt < 4; ++nt) {
            xi[nt] = __builtin_amdgcn_mfma_f32_16x16x32_bf16(av[0], bfr[nt][0], zero, 0, 0, 0);
            xi[nt] = __builtin_amdgcn_mfma_f32_16x16x32_bf16(av[1], bfr[nt][1], xi[nt], 0, 0, 0);
        }
        // no second fence: per-wave DS pipe is in-order

        // wei = rcp(1 + 2^(z + xge));  xi = xn*(1+wei)
#pragma unroll
        for (int nt = 0; nt < 4; ++nt)
#pragma unroll
            for (int r = 0; r < 4; ++r) {
                float e2  = exp2f(xi[nt][r] + xge[nt]);
                float wei = frcp(1.f + e2);
                float x   = xn[nt][r];
                xi[nt][r] = fmaf(x, wei, x);
            }

        const int fin = base + nb;
        if (fin <= end_cur) {
            if (nb == 16) {
#pragma unroll
                for (int nt = 0; nt < 4; ++nt)
#pragma unroll
                    for (int r = 0; r < 4; ++r) {
                        sm[nt] += xi[nt][r];
                        mxv[nt] = fmaxf(mxv[nt], xi[nt][r]);
                    }
            } else {
#pragma unroll
                for (int nt = 0; nt < 4; ++nt)
#pragma unroll
                    for (int r = 0; r < 4; ++r) {
                        bool act = (4 * q + r) < nb;
                        sm[nt] += act ? xi[nt][r] : 0.f;
                        mxv[nt] = fmaxf(mxv[nt], act ? xi[nt][r] : -INFINITY);
                    }
            }
            if (fin == end_cur) { flushseg(cur); ++cur; end_cur = st2; }
        } else {
            const int B = end_cur - base;   // 1..nb-1
#pragma unroll
            for (int nt = 0; nt < 4; ++nt)
#pragma unroll
                for (int r = 0; r < 4; ++r) {
                    bool act = (4 * q + r) < B;
                    sm[nt] += act ? xi[nt][r] : 0.f;
                    mxv[nt] = fmaxf(mxv[nt], act ? xi[nt][r] : -INFINITY);
                }
            flushseg(cur); ++cur;
#pragma unroll
            for (int nt = 0; nt < 4; ++nt)
#pragma unroll
                for (int r = 0; r < 4; ++r) {
                    int pt = 4 * q + r;
                    bool act = (pt >= B) && (pt < nb);
                    sm[nt] += act ? xi[nt][r] : 0.f;
                    mxv[nt] = fmaxf(mxv[nt], act ? xi[nt][r] : -INFINITY);
                }
            end_cur = st2;
        }
    }
}

extern "C" void kernel_launch(void* const* d_in, const int* in_sizes, int n_in,
                              void* d_out, int out_size, void* d_ws, size_t ws_size,
                              hipStream_t stream) {
    const float* inp   = (const float*)d_in[0];
    const int*   unq   = (const int*)d_in[1];
    const float* W     = (const float*)d_in[2];
    const float* gamma = (const float*)d_in[3];
    const float* beta  = (const float*)d_in[4];
    const float* dw1   = (const float*)d_in[5];
    const float* pw1   = (const float*)d_in[6];
    const float* dw2   = (const float*)d_in[7];
    const float* pw2   = (const float*)d_in[8];
    float* out = (float*)d_out;
    float* ws  = (float*)d_ws;
    int* starts = (int*)ws + 1024;

    hipMemsetAsync(ws, 0, 384 * sizeof(float), stream);   // zero accumulators

    k_moments <<<1024, 256, 0, stream>>>(inp, unq, ws, starts);
    k_gstats  <<<1024, 256, 0, stream>>>(inp, W, gamma, beta, ws);
    k_prep    <<<1,    64,  0, stream>>>(W, gamma, beta, dw1, pw1, dw2, pw2, ws);
    k_main    <<<7500, 128, 0, stream>>>(inp, ws, starts, out);
}